// Round 6
// baseline (16.705 us; speedup 1.0000x reference)
//
#include <hip/hip_runtime.h>
#include <hip/hip_bf16.h>

// Embedding gather with OOV handling.
// out[r][d] = (idx[r] >= VOCAB) ? oov[d] : emb[idx[r]][d]
// D = 200 floats = 50 float4 per row; rows are 800B => 16B aligned.
//
// R6: persistent grid-stride (800 WGs x 2 chunks) on top of the measured-best
// cache policy (cached gather loads + NT stores; R2=11.87us beat cached/cached
// 13.47 and NT-load 15.06). Theory: single-shot lockstep waves give a
// read-phase then write-drain tail with poor R/W overlap; a 2-iteration
// pipeline per wave lets iter-2 gathers issue while iter-1 NT stores are
// still in flight (vmcnt counted, not drained), overlapping the streams.

typedef float f32x4 __attribute__((ext_vector_type(4)));

#define ELEMS 4
#define BLOCK 256
#define CHUNK (BLOCK * ELEMS)   // 1024 float4 per chunk

__global__ void embed_gather_kernel(const int* __restrict__ indices,
                                    const f32x4* __restrict__ emb,
                                    const f32x4* __restrict__ oov,
                                    f32x4* __restrict__ out,
                                    int n_vec,      // total float4 elements in output
                                    int vocab,
                                    int nchunks) {
    for (int c = blockIdx.x; c < nchunks; c += gridDim.x) {
        int base = c * CHUNK + threadIdx.x;

        int   idx[ELEMS];
        int   off[ELEMS];
        f32x4 val[ELEMS];

        // Phase 1: index loads (cached; hot across lanes and replays)
        #pragma unroll
        for (int k = 0; k < ELEMS; ++k) {
            int i = base + k * BLOCK;
            int ii = (i < n_vec) ? i : 0;
            int row = ii / 50;          // magic-mul, cheap
            off[k] = ii - row * 50;
            idx[k] = indices[row];
        }

        // Phase 2: gather loads (cached; idx set constant across replays ->
        // ~22.6MB unique rows stay L2/L3-warm)
        #pragma unroll
        for (int k = 0; k < ELEMS; ++k) {
            const f32x4* src = (idx[k] >= vocab)
                             ? (oov + off[k])
                             : (emb + (long long)idx[k] * 50 + off[k]);
            val[k] = *src;
        }

        // Phase 3: nontemporal streaming stores (write-only output; measured
        // best vs cached stores). Next iteration's loads issue while these
        // are still in flight.
        #pragma unroll
        for (int k = 0; k < ELEMS; ++k) {
            int i = base + k * BLOCK;
            if (i < n_vec) {
                __builtin_nontemporal_store(val[k], out + i);
            }
        }
    }
}

extern "C" void kernel_launch(void* const* d_in, const int* in_sizes, int n_in,
                              void* d_out, int out_size, void* d_ws, size_t ws_size,
                              hipStream_t stream) {
    const int*   indices = (const int*)d_in[0];
    const float* emb     = (const float*)d_in[1];
    const float* oov     = (const float*)d_in[2];
    float*       out     = (float*)d_out;

    const int D      = in_sizes[2];            // 200
    const int vocab  = in_sizes[1] / D;        // 100000
    const int n_vec  = out_size / 4;           // float4 count

    const int nchunks = (n_vec + CHUNK - 1) / CHUNK;   // 1600
    int grid = nchunks < 800 ? nchunks : 800;          // 2 chunks per WG
    embed_gather_kernel<<<grid, BLOCK, 0, stream>>>(
        indices,
        (const f32x4*)emb,
        (const f32x4*)oov,
        (f32x4*)out,
        n_vec, vocab, nchunks);
}